// Round 1
// baseline (469.717 us; speedup 1.0000x reference)
//
#include <hip/hip_runtime.h>

#define HH 128
#define WW 128
#define CC 64
#define OO 64
#define KK 9
#define PLANE (HH * WW)

// wt[ck*64 + o] = weight[o*576 + ck]
__global__ void transpose_weight_kernel(const float* __restrict__ w,
                                        float* __restrict__ wt) {
    int i = blockIdx.x * 256 + threadIdx.x;
    if (i < CC * KK * OO) {
        int o = i & 63;
        int ck = i >> 6;
        wt[i] = w[o * (CC * KK) + ck];
    }
}

__global__ __launch_bounds__(256)
void deform_conv_kernel(const float* __restrict__ data,
                        const float* __restrict__ offset,
                        const float* __restrict__ wt,
                        float* __restrict__ out) {
    const int tid = threadIdx.x;
    const int wo = tid & 127;              // pixel within row
    int ohalf = tid >> 7;                  // 0 or 1 (wave-uniform: waves 0,1 vs 2,3)
    ohalf = __builtin_amdgcn_readfirstlane(ohalf);  // prove uniformity -> s_load weights

    const int row = blockIdx.x;            // b*128 + ho
    const int b = row >> 7;
    const int ho = row & 127;

    // ---- per-k bilinear descriptors (shared across all c) ----
    int abyte[KK][4];     // clamped corner byte offsets within a plane
    float wgt[KK][4];     // validity-masked bilinear weights

    const float* offBase = offset + ((size_t)b * 18) * PLANE + ho * WW + wo;
#pragma unroll
    for (int k = 0; k < KK; ++k) {
        float oy = offBase[(2 * k) * PLANE];
        float ox = offBase[(2 * k + 1) * PLANE];
        float py = oy + (float)(ho - 1 + k / 3);
        float px = ox + (float)(wo - 1 + k % 3);
        float y0f = floorf(py);
        float x0f = floorf(px);
        float wy1 = py - y0f, wx1 = px - x0f;
        float wy0 = 1.f - wy1, wx0 = 1.f - wx1;
        int y0 = (int)y0f, x0 = (int)x0f;
        int y1 = y0 + 1, x1 = x0 + 1;
        float my0 = (y0 >= 0 && y0 < HH) ? 1.f : 0.f;
        float my1 = (y1 >= 0 && y1 < HH) ? 1.f : 0.f;
        float mx0 = (x0 >= 0 && x0 < WW) ? 1.f : 0.f;
        float mx1 = (x1 >= 0 && x1 < WW) ? 1.f : 0.f;
        int yc0 = min(max(y0, 0), HH - 1);
        int yc1 = min(max(y1, 0), HH - 1);
        int xc0 = min(max(x0, 0), WW - 1);
        int xc1 = min(max(x1, 0), WW - 1);
        abyte[k][0] = (yc0 * WW + xc0) * 4;
        abyte[k][1] = (yc0 * WW + xc1) * 4;
        abyte[k][2] = (yc1 * WW + xc0) * 4;
        abyte[k][3] = (yc1 * WW + xc1) * 4;
        wgt[k][0] = wy0 * wx0 * my0 * mx0;
        wgt[k][1] = wy0 * wx1 * my0 * mx1;
        wgt[k][2] = wy1 * wx0 * my1 * mx0;
        wgt[k][3] = wy1 * wx1 * my1 * mx1;
    }

    float acc[32];
#pragma unroll
    for (int j = 0; j < 32; ++j) acc[j] = 0.f;

    const float* planeBase = data + (size_t)b * CC * PLANE;
    // weight rows: wt[ck*64 .. ck*64+63]; our half starts at ohalf*32
    const float4* wt4base = (const float4*)wt + ohalf * 8;

    for (int c = 0; c < CC; ++c) {
        const char* pc = (const char*)(planeBase + c * PLANE);  // uniform base (SGPR)
#pragma unroll
        for (int k = 0; k < KK; ++k) {
            float v00 = *(const float*)(pc + abyte[k][0]);
            float v01 = *(const float*)(pc + abyte[k][1]);
            float v10 = *(const float*)(pc + abyte[k][2]);
            float v11 = *(const float*)(pc + abyte[k][3]);
            float s = wgt[k][0] * v00 + wgt[k][1] * v01 +
                      wgt[k][2] * v10 + wgt[k][3] * v11;
            const float4* wp = wt4base + (c * KK + k) * 16;
#pragma unroll
            for (int j = 0; j < 8; ++j) {
                float4 wv = wp[j];   // uniform address -> s_load_dwordx4
                acc[4 * j + 0] += s * wv.x;
                acc[4 * j + 1] += s * wv.y;
                acc[4 * j + 2] += s * wv.z;
                acc[4 * j + 3] += s * wv.w;
            }
        }
    }

    float* outp = out + ((size_t)b * OO + ohalf * 32) * PLANE + ho * WW + wo;
#pragma unroll
    for (int j = 0; j < 32; ++j) outp[j * PLANE] = acc[j];
}

extern "C" void kernel_launch(void* const* d_in, const int* in_sizes, int n_in,
                              void* d_out, int out_size, void* d_ws, size_t ws_size,
                              hipStream_t stream) {
    const float* data = (const float*)d_in[0];    // (8,64,128,128)
    const float* offset = (const float*)d_in[1];  // (8,18,128,128)
    const float* weight = (const float*)d_in[2];  // (64,64,3,3)
    float* out = (float*)d_out;                   // (8,64,128,128)
    float* wt = (float*)d_ws;                     // 576*64 floats = 147456 B

    int nw = CC * KK * OO;
    transpose_weight_kernel<<<(nw + 255) / 256, 256, 0, stream>>>(weight, wt);

    dim3 grid(8 * HH);   // B * H rows
    deform_conv_kernel<<<grid, 256, 0, stream>>>(data, offset, wt, out);
}

// Round 2
// 236.162 us; speedup vs baseline: 1.9890x; 1.9890x over previous
//
#include <hip/hip_runtime.h>

#define HH 128
#define WW 128
#define CC 64
#define OO 64
#define KK 9
#define PLANE (HH * WW)

typedef short short8 __attribute__((ext_vector_type(8)));
typedef float floatx4 __attribute__((ext_vector_type(4)));

__device__ __forceinline__ unsigned bf16rne(float x) {
    unsigned a = __float_as_uint(x);
    return (a + 0x7fffu + ((a >> 16) & 1u)) >> 16;
}
__device__ __forceinline__ unsigned bf16pack(float lo, float hi) {
    unsigned a = __float_as_uint(lo);
    unsigned b = __float_as_uint(hi);
    unsigned lo16 = (a + 0x7fffu + ((a >> 16) & 1u)) >> 16;
    unsigned hi16 = (b + 0x7fffu + ((b >> 16) & 1u)) & 0xffff0000u;
    return lo16 | hi16;
}

// ---------- prep 1: NCHW f32 -> NHWC bf16 ----------
__global__ __launch_bounds__(256)
void nhwc_bf16_kernel(const float* __restrict__ in, unsigned short* __restrict__ outT) {
    __shared__ unsigned tile[64 * 36];   // [p][cpair], pad 36 dwords/row (144B, 16B-aligned rows)
    int blk = blockIdx.x;                // ((b*128 + y)*2 + xh)
    int xh = blk & 1;
    int y  = (blk >> 1) & 127;
    int b  = blk >> 8;
    int t = threadIdx.x;
    int p = t & 63;
    int cg = t >> 6;                     // 0..3
    const float* src = in + (size_t)(b * 64) * PLANE + y * WW + xh * 64 + p;
#pragma unroll
    for (int i = 0; i < 8; ++i) {
        int c0 = cg * 16 + 2 * i;
        float v0 = src[(size_t)c0 * PLANE];
        float v1 = src[(size_t)(c0 + 1) * PLANE];
        tile[p * 36 + (c0 >> 1)] = bf16pack(v0, v1);
    }
    __syncthreads();
    int p2 = t >> 2;
    int q = t & 3;
    const unsigned* s = &tile[p2 * 36 + q * 8];
    uint4 w0 = *(const uint4*)(s);
    uint4 w1 = *(const uint4*)(s + 4);
    unsigned* dst = (unsigned*)outT + (size_t)((b * 128 + y) * 128 + xh * 64) * 32 + (size_t)t * 8;
    *(uint4*)dst = w0;
    *(uint4*)(dst + 4) = w1;
}

// ---------- prep 2: weight (o,c,k) f32 -> wt2[k][o][c] bf16 ----------
__global__ void wprep_kernel(const float* __restrict__ w, unsigned short* __restrict__ wt2) {
    int t = blockIdx.x * 256 + threadIdx.x;
    if (t < KK * OO * CC) {
        int c = t & 63;
        int o = (t >> 6) & 63;
        int k = t >> 12;
        wt2[t] = (unsigned short)bf16rne(w[(o * 64 + c) * 9 + k]);
    }
}

// ---------- main: sample->LDS bf16 A-tile, MFMA vs weights ----------
__global__ __launch_bounds__(256)
void deform_mfma_kernel(const unsigned short* __restrict__ dataT,
                        const float* __restrict__ offset,
                        const unsigned short* __restrict__ wt2,
                        float* __restrict__ out) {
    __shared__ short sA[128 * 72];   // A[m=pixel][c], row stride 72 shorts (144B)
    __shared__ short sB[64 * 72];    // B[o][c]
    __shared__ float sD[128 * 8];    // per-pixel descriptor: base0,base1,wA0,wB0,wA1,wB1

    const int t = threadIdx.x;
    const int lane = t & 63;
    const int w = t >> 6;            // wave id 0..3
    const int quad = lane >> 4;
    const int l15 = lane & 15;
    const int row = blockIdx.x;      // b*128 + ho
    const int b = row >> 7;
    const int ho = row & 127;

    floatx4 acc[2][4];
#pragma unroll
    for (int mt = 0; mt < 2; ++mt)
#pragma unroll
        for (int nt = 0; nt < 4; ++nt)
            acc[mt][nt] = (floatx4){0.f, 0.f, 0.f, 0.f};

    for (int k = 0; k < KK; ++k) {
        // ---- stage weight tile for this k ----
        {
            const uint4* g = (const uint4*)(wt2 + k * 4096);
            uint4 w0 = g[t * 2];
            uint4 w1 = g[t * 2 + 1];
            int o = t >> 2;
            int c0 = (t & 3) * 16;
            *(uint4*)&sB[o * 72 + c0] = w0;
            *(uint4*)&sB[o * 72 + c0 + 8] = w1;
        }
        // ---- per-pixel bilinear descriptors (threads 0..127, pixel = t) ----
        if (t < 128) {
            const float* offp = offset + (size_t)(b * 18) * PLANE + ho * WW + t;
            float oy = offp[(size_t)(2 * k) * PLANE];
            float ox = offp[(size_t)(2 * k + 1) * PLANE];
            float py = (float)(ho - 1 + k / 3) + oy;
            float px = (float)(t - 1 + k % 3) + ox;
            float y0f = floorf(py);
            float x0f = floorf(px);
            float fy = py - y0f;
            float fx = px - x0f;
            int y0 = (int)y0f;
            int x0 = (int)x0f;
            int y1 = y0 + 1;
            int x1 = x0 + 1;
            float wy0 = (1.f - fy) * ((y0 >= 0 && y0 < HH) ? 1.f : 0.f);
            float wy1 = fy * ((y1 >= 0 && y1 < HH) ? 1.f : 0.f);
            float wx0 = (1.f - fx) * ((x0 >= 0 && x0 < WW) ? 1.f : 0.f);
            float wx1 = fx * ((x1 >= 0 && x1 < WW) ? 1.f : 0.f);
            int yc0 = min(max(y0, 0), HH - 1);
            int yc1 = min(max(y1, 0), HH - 1);
            int x_lo = min(max(x0, 0), WW - 2);
            // weight for data at x_lo (half A) and x_lo+1 (half B), edge-safe
            float wA = ((x0 == x_lo) ? wx0 : 0.f) + ((x1 == x_lo) ? wx1 : 0.f);
            float wB = ((x0 == x_lo + 1) ? wx0 : 0.f) + ((x1 == x_lo + 1) ? wx1 : 0.f);
            unsigned base0 = (unsigned)(((b * 128 + yc0) * 128 + x_lo) * 128); // bytes in NHWC bf16
            unsigned base1 = (unsigned)(((b * 128 + yc1) * 128 + x_lo) * 128);
            float* d = &sD[t * 8];
            d[0] = __uint_as_float(base0);
            d[1] = __uint_as_float(base1);
            d[2] = wy0 * wA;
            d[3] = wy0 * wB;
            d[4] = wy1 * wA;
            d[5] = wy1 * wB;
        }
        __syncthreads();

        // ---- sampling: wave w produces A rows [w*32, w*32+32) ----
        const unsigned loff = (unsigned)(lane * 4);
        const bool lowHalf = (lane < 32);
#pragma unroll 4
        for (int i = 0; i < 32; ++i) {
            int px = w * 32 + i;
            const float* d = &sD[px * 8];
            float4 dA = *(const float4*)d;          // broadcast reads
            float2 dB = *(const float2*)(d + 4);
            unsigned base0 = __float_as_uint(dA.x);
            unsigned base1 = __float_as_uint(dA.y);
            float wr0 = lowHalf ? dA.z : dA.w;
            float wr1 = lowHalf ? dB.x : dB.y;
            unsigned u0 = *(const unsigned*)((const char*)dataT + base0 + loff);
            unsigned u1 = *(const unsigned*)((const char*)dataT + base1 + loff);
            float lo0 = __uint_as_float(u0 << 16);
            float hi0 = __uint_as_float(u0 & 0xffff0000u);
            float lo1 = __uint_as_float(u1 << 16);
            float hi1 = __uint_as_float(u1 & 0xffff0000u);
            float tl = lo0 * wr0 + lo1 * wr1;
            float th = hi0 * wr0 + hi1 * wr1;
            tl += __shfl_xor(tl, 32);
            th += __shfl_xor(th, 32);
            if (lowHalf) {
                *(unsigned*)&sA[px * 72 + lane * 2] = bf16pack(tl, th);
            }
        }
        // sA rows are produced and consumed by the same wave; sB/sD already synced

        // ---- MFMA: wave w computes pixels [w*32, w*32+32) x all 64 o ----
        const int mbase = w * 32;
#pragma unroll
        for (int step = 0; step < 2; ++step) {
            short8 a0 = *(const short8*)&sA[(mbase + l15) * 72 + step * 32 + quad * 8];
            short8 a1 = *(const short8*)&sA[(mbase + 16 + l15) * 72 + step * 32 + quad * 8];
#pragma unroll
            for (int nt = 0; nt < 4; ++nt) {
                short8 bf = *(const short8*)&sB[(nt * 16 + l15) * 72 + step * 32 + quad * 8];
                acc[0][nt] = __builtin_amdgcn_mfma_f32_16x16x32_bf16(a0, bf, acc[0][nt], 0, 0, 0);
                acc[1][nt] = __builtin_amdgcn_mfma_f32_16x16x32_bf16(a1, bf, acc[1][nt], 0, 0, 0);
            }
        }
        __syncthreads();   // protect sB/sD for next k
    }

    // ---- epilogue: D col=lane&15 (=o), row=quad*4+reg (=pixel) ----
#pragma unroll
    for (int mt = 0; mt < 2; ++mt)
#pragma unroll
        for (int nt = 0; nt < 4; ++nt) {
            int o = nt * 16 + l15;
            int px = w * 32 + mt * 16 + quad * 4;
            float* dst = out + (size_t)(b * 64 + o) * PLANE + ho * 128 + px;
            *(floatx4*)dst = acc[mt][nt];
        }
}

// ================= fallback (round-1 scalar path) =================
__global__ void transpose_weight_kernel(const float* __restrict__ w,
                                        float* __restrict__ wt) {
    int i = blockIdx.x * 256 + threadIdx.x;
    if (i < CC * KK * OO) {
        int o = i & 63;
        int ck = i >> 6;
        wt[i] = w[o * (CC * KK) + ck];
    }
}

__global__ __launch_bounds__(256)
void deform_conv_kernel(const float* __restrict__ data,
                        const float* __restrict__ offset,
                        const float* __restrict__ wt,
                        float* __restrict__ out) {
    const int tid = threadIdx.x;
    const int wo = tid & 127;
    int ohalf = tid >> 7;
    ohalf = __builtin_amdgcn_readfirstlane(ohalf);
    const int row = blockIdx.x;
    const int b = row >> 7;
    const int ho = row & 127;
    int abyte[KK][4];
    float wgt[KK][4];
    const float* offBase = offset + ((size_t)b * 18) * PLANE + ho * WW + wo;
#pragma unroll
    for (int k = 0; k < KK; ++k) {
        float oy = offBase[(2 * k) * PLANE];
        float ox = offBase[(2 * k + 1) * PLANE];
        float py = oy + (float)(ho - 1 + k / 3);
        float px = ox + (float)(wo - 1 + k % 3);
        float y0f = floorf(py);
        float x0f = floorf(px);
        float wy1 = py - y0f, wx1 = px - x0f;
        float wy0 = 1.f - wy1, wx0 = 1.f - wx1;
        int y0 = (int)y0f, x0 = (int)x0f;
        int y1 = y0 + 1, x1 = x0 + 1;
        float my0 = (y0 >= 0 && y0 < HH) ? 1.f : 0.f;
        float my1 = (y1 >= 0 && y1 < HH) ? 1.f : 0.f;
        float mx0 = (x0 >= 0 && x0 < WW) ? 1.f : 0.f;
        float mx1 = (x1 >= 0 && x1 < WW) ? 1.f : 0.f;
        int yc0 = min(max(y0, 0), HH - 1);
        int yc1 = min(max(y1, 0), HH - 1);
        int xc0 = min(max(x0, 0), WW - 1);
        int xc1 = min(max(x1, 0), WW - 1);
        abyte[k][0] = (yc0 * WW + xc0) * 4;
        abyte[k][1] = (yc0 * WW + xc1) * 4;
        abyte[k][2] = (yc1 * WW + xc0) * 4;
        abyte[k][3] = (yc1 * WW + xc1) * 4;
        wgt[k][0] = wy0 * wx0 * my0 * mx0;
        wgt[k][1] = wy0 * wx1 * my0 * mx1;
        wgt[k][2] = wy1 * wx0 * my1 * mx0;
        wgt[k][3] = wy1 * wx1 * my1 * mx1;
    }
    float acc[32];
#pragma unroll
    for (int j = 0; j < 32; ++j) acc[j] = 0.f;
    const float* planeBase = data + (size_t)b * CC * PLANE;
    const float4* wt4base = (const float4*)wt + ohalf * 8;
    for (int c = 0; c < CC; ++c) {
        const char* pc = (const char*)(planeBase + c * PLANE);
#pragma unroll
        for (int k = 0; k < KK; ++k) {
            float v00 = *(const float*)(pc + abyte[k][0]);
            float v01 = *(const float*)(pc + abyte[k][1]);
            float v10 = *(const float*)(pc + abyte[k][2]);
            float v11 = *(const float*)(pc + abyte[k][3]);
            float s = wgt[k][0] * v00 + wgt[k][1] * v01 +
                      wgt[k][2] * v10 + wgt[k][3] * v11;
            const float4* wp = wt4base + (c * KK + k) * 16;
#pragma unroll
            for (int j = 0; j < 8; ++j) {
                float4 wv = wp[j];
                acc[4 * j + 0] += s * wv.x;
                acc[4 * j + 1] += s * wv.y;
                acc[4 * j + 2] += s * wv.z;
                acc[4 * j + 3] += s * wv.w;
            }
        }
    }
    float* outp = out + ((size_t)b * OO + ohalf * 32) * PLANE + ho * WW + wo;
#pragma unroll
    for (int j = 0; j < 32; ++j) outp[j * PLANE] = acc[j];
}

extern "C" void kernel_launch(void* const* d_in, const int* in_sizes, int n_in,
                              void* d_out, int out_size, void* d_ws, size_t ws_size,
                              hipStream_t stream) {
    const float* data = (const float*)d_in[0];    // (8,64,128,128) f32
    const float* offset = (const float*)d_in[1];  // (8,18,128,128) f32
    const float* weight = (const float*)d_in[2];  // (64,64,3,3) f32
    float* out = (float*)d_out;                   // (8,64,128,128) f32

    const size_t DATA_T_BYTES = (size_t)8 * 128 * 128 * 64 * 2;   // 16,777,216
    const size_t WT2_BYTES = (size_t)KK * OO * CC * 2;            // 73,728

    if (ws_size >= DATA_T_BYTES + WT2_BYTES) {
        unsigned short* dataT = (unsigned short*)d_ws;
        unsigned short* wt2 = (unsigned short*)((char*)d_ws + DATA_T_BYTES);
        nhwc_bf16_kernel<<<8 * 128 * 2, 256, 0, stream>>>(data, dataT);
        wprep_kernel<<<(KK * OO * CC + 255) / 256, 256, 0, stream>>>(weight, wt2);
        deform_mfma_kernel<<<8 * HH, 256, 0, stream>>>(dataT, offset, wt2, out);
    } else {
        float* wt = (float*)d_ws;
        int nw = CC * KK * OO;
        transpose_weight_kernel<<<(nw + 255) / 256, 256, 0, stream>>>(weight, wt);
        deform_conv_kernel<<<8 * HH, 256, 0, stream>>>(data, offset, wt, out);
    }
}

// Round 3
// 142.929 us; speedup vs baseline: 3.2864x; 1.6523x over previous
//
#include <hip/hip_runtime.h>

#define HH 128
#define WW 128
#define CC 64
#define OO 64
#define KK 9
#define PLANE (HH * WW)

typedef short short8 __attribute__((ext_vector_type(8)));
typedef float floatx4 __attribute__((ext_vector_type(4)));

__device__ __forceinline__ unsigned bf16r(float x) {
    unsigned a = __float_as_uint(x);
    return (a + 0x7fffu + ((a >> 16) & 1u)) >> 16;
}
__device__ __forceinline__ unsigned bf16pack(float lo, float hi) {
    unsigned a = __float_as_uint(lo);
    unsigned b = __float_as_uint(hi);
    return ((a + 0x7fffu + ((a >> 16) & 1u)) >> 16) |
           ((b + 0x7fffu + ((b >> 16) & 1u)) & 0xffff0000u);
}
__device__ __forceinline__ float lo16f(unsigned u) { return __uint_as_float(u << 16); }
__device__ __forceinline__ float hi16f(unsigned u) { return __uint_as_float(u & 0xffff0000u); }

// ---------- prep 1: NCHW f32 -> NHWC bf16 (XCD-swizzled: batch = blk&7) ----------
__global__ __launch_bounds__(256)
void nhwc_bf16_kernel(const float* __restrict__ in, unsigned short* __restrict__ outT) {
    __shared__ unsigned tile[64 * 36];
    int raw = blockIdx.x;
    int b = raw & 7;
    int rest = raw >> 3;         // 0..255
    int y = rest >> 1;
    int xh = rest & 1;
    int t = threadIdx.x;
    int p = t & 63;
    int cg = t >> 6;
    const float* src = in + (size_t)(b * 64) * PLANE + y * WW + xh * 64 + p;
#pragma unroll
    for (int i = 0; i < 4; ++i) {
        int c0 = cg * 16 + 4 * i;
        float v0 = src[(size_t)(c0 + 0) * PLANE];
        float v1 = src[(size_t)(c0 + 1) * PLANE];
        float v2 = src[(size_t)(c0 + 2) * PLANE];
        float v3 = src[(size_t)(c0 + 3) * PLANE];
        uint2 dd;
        dd.x = bf16pack(v0, v1);
        dd.y = bf16pack(v2, v3);
        *(uint2*)&tile[p * 36 + (c0 >> 1)] = dd;   // b64 write
    }
    __syncthreads();
    int p2 = t >> 2;
    int q = t & 3;
    const unsigned* s = &tile[p2 * 36 + q * 8];
    uint4 w0 = *(const uint4*)s;
    uint4 w1 = *(const uint4*)(s + 4);
    unsigned* dst = (unsigned*)outT + (size_t)((b * 128 + y) * 128 + xh * 64) * 32 + (size_t)t * 8;
    *(uint4*)dst = w0;
    *(uint4*)(dst + 4) = w1;
}

// ---------- prep 2: weight -> MFMA B-fragment layout wt3[k][step*4+nt][lane][8] bf16 ----------
__global__ void wprep_kernel(const float* __restrict__ w, unsigned short* __restrict__ wt3) {
    int idx = blockIdx.x * 256 + threadIdx.x;
    if (idx < KK * 8 * 64 * 8) {
        int j = idx & 7;
        int lane = (idx >> 3) & 63;
        int f = (idx >> 9) & 7;
        int k = idx >> 12;
        int nt = f & 3;
        int step = f >> 2;
        int l15 = lane & 15;
        int quad = lane >> 4;
        int o = nt * 16 + l15;
        int c = step * 32 + quad * 8 + j;
        wt3[idx] = (unsigned short)bf16r(w[(o * 64 + c) * 9 + k]);
    }
}

// ---------- main: barrier-free k-loop, register B-frags, same-wave sA ----------
__global__ __launch_bounds__(256, 4)
void deform_mfma_kernel(const unsigned short* __restrict__ dataT,
                        const float* __restrict__ offset,
                        const unsigned short* __restrict__ wt3,
                        float* __restrict__ out) {
    __shared__ uint4 sD[KK][128];    // 18.4 KB: base0, base1, bf16(w01|w00), bf16(w11|w10)
    __shared__ short sA[128 * 72];   // 18.4 KB: A[m=pixel][c], row 144B

    const int t = threadIdx.x;
    const int lane = t & 63;
    const int w = t >> 6;
    const int quad = lane >> 4;
    const int l15 = lane & 15;
    const int l5 = lane & 31;
    const int half = lane >> 5;
    const int raw = blockIdx.x;
    const int b = raw & 7;       // XCD-aligned batch
    const int ho = raw >> 3;

    // ---- all 9k descriptors, once ----
    {
        int px = t & 127;
        const float* offp = offset + (size_t)(b * 18) * PLANE + ho * WW + px;
        int k0 = (t < 128) ? 0 : 1;
        for (int k = k0; k < KK; k += 2) {
            float oy = offp[(size_t)(2 * k) * PLANE];
            float ox = offp[(size_t)(2 * k + 1) * PLANE];
            float py = (float)(ho - 1 + k / 3) + oy;
            float pxx = (float)(px - 1 + k % 3) + ox;
            float y0f = floorf(py);
            float x0f = floorf(pxx);
            float fy = py - y0f;
            float fx = pxx - x0f;
            int y0 = (int)y0f, x0 = (int)x0f;
            int y1 = y0 + 1, x1 = x0 + 1;
            float wy0 = (1.f - fy) * ((y0 >= 0 && y0 < HH) ? 1.f : 0.f);
            float wy1 = fy * ((y1 >= 0 && y1 < HH) ? 1.f : 0.f);
            float wx0 = (1.f - fx) * ((x0 >= 0 && x0 < WW) ? 1.f : 0.f);
            float wx1 = fx * ((x1 >= 0 && x1 < WW) ? 1.f : 0.f);
            int yc0 = min(max(y0, 0), HH - 1);
            int yc1 = min(max(y1, 0), HH - 1);
            int x_lo = min(max(x0, 0), WW - 2);
            float wA = ((x0 == x_lo) ? wx0 : 0.f) + ((x1 == x_lo) ? wx1 : 0.f);
            float wB = ((x0 == x_lo + 1) ? wx0 : 0.f) + ((x1 == x_lo + 1) ? wx1 : 0.f);
            uint4 d;
            d.x = (unsigned)(((b * 128 + yc0) * 128 + x_lo) * 128);
            d.y = (unsigned)(((b * 128 + yc1) * 128 + x_lo) * 128);
            d.z = bf16pack(wy0 * wA, wy0 * wB);
            d.w = bf16pack(wy1 * wA, wy1 * wB);
            sD[k][px] = d;
        }
    }
    __syncthreads();   // the ONLY barrier

    floatx4 acc[2][4];
#pragma unroll
    for (int mt = 0; mt < 2; ++mt)
#pragma unroll
        for (int nt = 0; nt < 4; ++nt)
            acc[mt][nt] = (floatx4){0.f, 0.f, 0.f, 0.f};

    const int mbase = w * 32;
    const char* dbase = (const char*)dataT;

    for (int k = 0; k < KK; ++k) {
        // B fragments straight to registers (coalesced, L2-hot 73KB table)
        short8 bfrag[8];
        const short* wk = (const short*)wt3 + k * 4096 + lane * 8;
#pragma unroll
        for (int f = 0; f < 8; ++f) bfrag[f] = *(const short8*)(wk + f * 512);

        // sampling: 2 pixels/iter (lanes 0-31 -> pxA, 32-63 -> pxB), no shfl
#pragma unroll
        for (int i = 0; i < 16; ++i) {
            int px = mbase + 2 * i + half;
            uint4 d = sD[k][px];
            unsigned a0 = d.x + l5 * 4;
            unsigned a1 = d.y + l5 * 4;
            unsigned u00 = *(const unsigned*)(dbase + a0);
            unsigned u01 = *(const unsigned*)(dbase + a0 + 128);
            unsigned u10 = *(const unsigned*)(dbase + a1);
            unsigned u11 = *(const unsigned*)(dbase + a1 + 128);
            float w00 = lo16f(d.z), w01 = hi16f(d.z);
            float w10 = lo16f(d.w), w11 = hi16f(d.w);
            float slo = lo16f(u00) * w00 + lo16f(u01) * w01 + lo16f(u10) * w10 + lo16f(u11) * w11;
            float shi = hi16f(u00) * w00 + hi16f(u01) * w01 + hi16f(u10) * w10 + hi16f(u11) * w11;
            *(unsigned*)&sA[px * 72 + l5 * 2] = bf16pack(slo, shi);
        }

        // MFMA (same-wave sA -> no barrier; compiler orders via lgkmcnt)
#pragma unroll
        for (int step = 0; step < 2; ++step) {
            short8 a0 = *(const short8*)&sA[(mbase + l15) * 72 + step * 32 + quad * 8];
            short8 a1 = *(const short8*)&sA[(mbase + 16 + l15) * 72 + step * 32 + quad * 8];
#pragma unroll
            for (int nt = 0; nt < 4; ++nt) {
                acc[0][nt] = __builtin_amdgcn_mfma_f32_16x16x32_bf16(a0, bfrag[step * 4 + nt], acc[0][nt], 0, 0, 0);
                acc[1][nt] = __builtin_amdgcn_mfma_f32_16x16x32_bf16(a1, bfrag[step * 4 + nt], acc[1][nt], 0, 0, 0);
            }
        }
    }

    // epilogue: D col=lane&15 (=o), row=quad*4+reg (=pixel)
#pragma unroll
    for (int mt = 0; mt < 2; ++mt)
#pragma unroll
        for (int nt = 0; nt < 4; ++nt) {
            int o = nt * 16 + l15;
            int px = mbase + mt * 16 + quad * 4;
            float* dst = out + (size_t)(b * 64 + o) * PLANE + ho * 128 + px;
            *(floatx4*)dst = acc[mt][nt];
        }
}

// ================= fallback (round-1 scalar path) =================
__global__ void transpose_weight_kernel(const float* __restrict__ w,
                                        float* __restrict__ wt) {
    int i = blockIdx.x * 256 + threadIdx.x;
    if (i < CC * KK * OO) {
        int o = i & 63;
        int ck = i >> 6;
        wt[i] = w[o * (CC * KK) + ck];
    }
}

__global__ __launch_bounds__(256)
void deform_conv_kernel(const float* __restrict__ data,
                        const float* __restrict__ offset,
                        const float* __restrict__ wt,
                        float* __restrict__ out) {
    const int tid = threadIdx.x;
    const int wo = tid & 127;
    int ohalf = tid >> 7;
    ohalf = __builtin_amdgcn_readfirstlane(ohalf);
    const int row = blockIdx.x;
    const int b = row >> 7;
    const int ho = row & 127;
    int abyte[KK][4];
    float wgt[KK][4];
    const float* offBase = offset + ((size_t)b * 18) * PLANE + ho * WW + wo;
#pragma unroll
    for (int k = 0; k < KK; ++k) {
        float oy = offBase[(2 * k) * PLANE];
        float ox = offBase[(2 * k + 1) * PLANE];
        float py = oy + (float)(ho - 1 + k / 3);
        float px = ox + (float)(wo - 1 + k % 3);
        float y0f = floorf(py);
        float x0f = floorf(px);
        float wy1 = py - y0f, wx1 = px - x0f;
        float wy0 = 1.f - wy1, wx0 = 1.f - wx1;
        int y0 = (int)y0f, x0 = (int)x0f;
        int y1 = y0 + 1, x1 = x0 + 1;
        float my0 = (y0 >= 0 && y0 < HH) ? 1.f : 0.f;
        float my1 = (y1 >= 0 && y1 < HH) ? 1.f : 0.f;
        float mx0 = (x0 >= 0 && x0 < WW) ? 1.f : 0.f;
        float mx1 = (x1 >= 0 && x1 < WW) ? 1.f : 0.f;
        int yc0 = min(max(y0, 0), HH - 1);
        int yc1 = min(max(y1, 0), HH - 1);
        int xc0 = min(max(x0, 0), WW - 1);
        int xc1 = min(max(x1, 0), WW - 1);
        abyte[k][0] = (yc0 * WW + xc0) * 4;
        abyte[k][1] = (yc0 * WW + xc1) * 4;
        abyte[k][2] = (yc1 * WW + xc0) * 4;
        abyte[k][3] = (yc1 * WW + xc1) * 4;
        wgt[k][0] = wy0 * wx0 * my0 * mx0;
        wgt[k][1] = wy0 * wx1 * my0 * mx1;
        wgt[k][2] = wy1 * wx0 * my1 * mx0;
        wgt[k][3] = wy1 * wx1 * my1 * mx1;
    }
    float acc[32];
#pragma unroll
    for (int j = 0; j < 32; ++j) acc[j] = 0.f;
    const float* planeBase = data + (size_t)b * CC * PLANE;
    const float4* wt4base = (const float4*)wt + ohalf * 8;
    for (int c = 0; c < CC; ++c) {
        const char* pc = (const char*)(planeBase + c * PLANE);
#pragma unroll
        for (int k = 0; k < KK; ++k) {
            float v00 = *(const float*)(pc + abyte[k][0]);
            float v01 = *(const float*)(pc + abyte[k][1]);
            float v10 = *(const float*)(pc + abyte[k][2]);
            float v11 = *(const float*)(pc + abyte[k][3]);
            float s = wgt[k][0] * v00 + wgt[k][1] * v01 +
                      wgt[k][2] * v10 + wgt[k][3] * v11;
            const float4* wp = wt4base + (c * KK + k) * 16;
#pragma unroll
            for (int j = 0; j < 8; ++j) {
                float4 wv = wp[j];
                acc[4 * j + 0] += s * wv.x;
                acc[4 * j + 1] += s * wv.y;
                acc[4 * j + 2] += s * wv.z;
                acc[4 * j + 3] += s * wv.w;
            }
        }
    }
    float* outp = out + ((size_t)b * OO + ohalf * 32) * PLANE + ho * WW + wo;
#pragma unroll
    for (int j = 0; j < 32; ++j) outp[j * PLANE] = acc[j];
}

extern "C" void kernel_launch(void* const* d_in, const int* in_sizes, int n_in,
                              void* d_out, int out_size, void* d_ws, size_t ws_size,
                              hipStream_t stream) {
    const float* data = (const float*)d_in[0];    // (8,64,128,128) f32
    const float* offset = (const float*)d_in[1];  // (8,18,128,128) f32
    const float* weight = (const float*)d_in[2];  // (64,64,3,3) f32
    float* out = (float*)d_out;                   // (8,64,128,128) f32

    const size_t DATA_T_BYTES = (size_t)8 * 128 * 128 * 64 * 2;   // 16,777,216
    const size_t WT3_BYTES = (size_t)KK * 8 * 64 * 8 * 2;         // 73,728

    if (ws_size >= DATA_T_BYTES + WT3_BYTES) {
        unsigned short* dataT = (unsigned short*)d_ws;
        unsigned short* wt3 = (unsigned short*)((char*)d_ws + DATA_T_BYTES);
        nhwc_bf16_kernel<<<8 * 128 * 2, 256, 0, stream>>>(data, dataT);
        wprep_kernel<<<(KK * 8 * 64 * 8 + 255) / 256, 256, 0, stream>>>(weight, wt3);
        deform_mfma_kernel<<<8 * HH, 256, 0, stream>>>(dataT, offset, wt3, out);
    } else {
        float* wt = (float*)d_ws;
        int nw = CC * KK * OO;
        transpose_weight_kernel<<<(nw + 255) / 256, 256, 0, stream>>>(weight, wt);
        deform_conv_kernel<<<8 * HH, 256, 0, stream>>>(data, offset, wt, out);
    }
}